// Round 12
// baseline (346.986 us; speedup 1.0000x reference)
//
#include <hip/hip_runtime.h>

#define TPB 256
#define HWSZ 9216      // 96*96

typedef __attribute__((ext_vector_type(8))) short short8x;
typedef __attribute__((ext_vector_type(4))) float f32x4;
typedef unsigned short ushort_t;
typedef unsigned int uint_t;

__device__ __forceinline__ float sigf(float v) { return 1.0f / (1.0f + __expf(-v)); }

__device__ __forceinline__ ushort_t f2bf(float f) {
  uint_t u = __float_as_uint(f);
  u = (u + 0x7fffu + ((u >> 16) & 1u)) >> 16;
  return (ushort_t)u;
}
__device__ __forceinline__ float bf2f(ushort_t h) {
  return __uint_as_float(((uint_t)h) << 16);
}

// fp32 epilogue-LDS swizzle (1024B rows): bijective, conflict-free columns
__device__ __forceinline__ int swz32(int p, int c) {
  return p * 1024 + ((((c * 4) ^ ((p & 7) << 4)) ^ (((p >> 3) & 3) << 2)));
}

// ---------------- pack weights to fragment-major bf16 ----------------
// 16x16x32 B-frag tile(kt,nt): elem(l,j) = B[kt*32+(l>>4)*8+j][nt*16+(l&15)]
// Gp:  [dir4][kt8][nt16][64][8]
// Ftp: [kt8][nt16][64][8]
// W1p: [kt8][pb32][ag2][64][8]  (pair-block pb = u-cols pb*16..+15; ag=0 a, 1 g)
// W2p: [kt16][nt16][64][8]
__global__ __launch_bounds__(TPB) void k_pack(
    const float* __restrict__ lrg, const float* __restrict__ rlg,
    const float* __restrict__ tbg, const float* __restrict__ btg,
    const float* __restrict__ fusew, const float* __restrict__ ff1w,
    const float* __restrict__ ff2w,
    ushort_t* __restrict__ Gp, ushort_t* __restrict__ Ftp,
    ushort_t* __restrict__ W1p, ushort_t* __restrict__ W2p) {
  int i = blockIdx.x * TPB + threadIdx.x;
  if (i < 262144) {
    int d = i >> 16, r = i & 65535;
    int kt = r >> 13, nt = (r >> 9) & 15, l = (r >> 3) & 63, j = r & 7;
    int k = kt * 32 + (l >> 4) * 8 + j;
    int n_ = nt * 16 + (l & 15);
    const float* g = (d == 0) ? lrg : (d == 1) ? rlg : (d == 2) ? tbg : btg;
    Gp[i] = f2bf(g[n_ * 256 + k]);
  } else if (i < 327680) {
    int r = i - 262144;
    int kt = r >> 13, nt = (r >> 9) & 15, l = (r >> 3) & 63, j = r & 7;
    int k = kt * 32 + (l >> 4) * 8 + j;
    int n_ = nt * 16 + (l & 15);
    Ftp[r] = f2bf(fusew[n_ * 256 + k]);
  } else if (i < 589824) {
    int r = i - 327680;
    int kt = r >> 15, pb = (r >> 10) & 31, ag = (r >> 9) & 1;
    int l = (r >> 3) & 63, j = r & 7;
    int k = kt * 32 + (l >> 4) * 8 + j;
    int colb = pb * 16 + (l & 15);
    int col = ag ? (512 + colb) : colb;
    W1p[r] = f2bf(ff1w[col * 256 + k]);
  } else if (i < 720896) {
    int r = i - 589824;
    int kt = r >> 13, nt = (r >> 9) & 15, l = (r >> 3) & 63, j = r & 7;
    int k = kt * 32 + (l >> 4) * 8 + j;
    int n_ = nt * 16 + (l & 15);
    W2p[r] = f2bf(ff2w[n_ * 512 + k]);
  }
}

// ---------------- per-(n,c) LayerNorm2d stats (float4) ----------------
__global__ __launch_bounds__(TPB) void k_stats(const float* __restrict__ src,
                                               float* __restrict__ mean,
                                               float* __restrict__ rstd) {
  int nc = blockIdx.x;
  const float4* p = (const float4*)(src + (long)nc * HWSZ);
  float s = 0.f, s2 = 0.f;
  for (int i = threadIdx.x; i < 2304; i += TPB) {
    float4 v = p[i];
    s += (v.x + v.y) + (v.z + v.w);
    s2 = fmaf(v.x, v.x, fmaf(v.y, v.y, fmaf(v.z, v.z, fmaf(v.w, v.w, s2))));
  }
#pragma unroll
  for (int off = 32; off > 0; off >>= 1) {
    s += __shfl_down(s, off);
    s2 += __shfl_down(s2, off);
  }
  __shared__ float ls[4], ls2[4];
  int lane = threadIdx.x & 63, wv = threadIdx.x >> 6;
  if (lane == 0) { ls[wv] = s; ls2[wv] = s2; }
  __syncthreads();
  if (threadIdx.x == 0) {
    float S = ls[0] + ls[1] + ls[2] + ls[3];
    float S2 = ls2[0] + ls2[1] + ls2[2] + ls2[3];
    float m = S * (1.0f / HWSZ);
    float var = S2 * (1.0f / HWSZ) - m * m;
    mean[nc] = m;
    rstd[nc] = rsqrtf(fmaxf(var, 0.f) + 1e-6f);
  }
}

// ---------------- ln1 + depthwise 3x3 -> y (NHWC) and yT (transposed) -------
// Block = (n, 4-row band, 32-ch group). Grid 8*24*8 = 1536.
__global__ __launch_bounds__(TPB) void k_lndw(
    const float* __restrict__ x, const float* __restrict__ mean1,
    const float* __restrict__ rstd1, const float* __restrict__ ln1w,
    const float* __restrict__ ln1b, const float* __restrict__ dww,
    const float* __restrict__ dwb, ushort_t* __restrict__ y,
    ushort_t* __restrict__ yT) {
  __shared__ __align__(16) ushort_t xs[6 * 32 * 104];   // 39936 B
  __shared__ __align__(16) ushort_t ot[2 * 96 * 32];    // 12288 B
  __shared__ float sc[32], sh[32];

  int tid = threadIdx.x;
  int bid = blockIdx.x;
  int cb = (bid & 7) * 32;
  int hb = (bid >> 3) % 24;
  int n  = bid / 192;
  int h0 = hb * 4;

  if (tid < 32) {
    int c = cb + tid;
    int nc = n * 256 + c;
    float scale = rstd1[nc] * ln1w[c];
    sc[tid] = scale;
    sh[tid] = ln1b[c] - mean1[nc] * scale;
  }
  if (tid < 192) {   // w halos
    xs[tid * 104 + 3] = 0;
    xs[tid * 104 + 100] = 0;
  }
  __syncthreads();

  // stage 6 LN'd rows (h0-1 .. h0+4), float4 loads -> bf16x4 stores
  for (int i = tid; i < 4608; i += TPB) {
    int rc = i / 24;            // 0..191  (row*32 + c)
    int f4 = i - rc * 24;       // 0..23
    int row = rc >> 5, c = rc & 31;
    int hh = h0 - 1 + row;
    uint2 pk = make_uint2(0, 0);
    if (hh >= 0 && hh < 96) {
      float4 v = *(const float4*)(x + (long)(n * 256 + cb + c) * HWSZ +
                                  hh * 96 + f4 * 4);
      float scale = sc[c], shift = sh[c];
      ushort_t p0 = f2bf(fmaf(v.x, scale, shift));
      ushort_t p1 = f2bf(fmaf(v.y, scale, shift));
      ushort_t p2 = f2bf(fmaf(v.z, scale, shift));
      ushort_t p3 = f2bf(fmaf(v.w, scale, shift));
      pk.x = (uint_t)p0 | ((uint_t)p1 << 16);
      pk.y = (uint_t)p2 | ((uint_t)p3 << 16);
    }
    *(uint2*)(xs + rc * 104 + 4 + f4 * 4) = pk;
  }
  __syncthreads();

  // conv: thread = (c = tid&31, 12-w group grp = tid>>5)
  int c = tid & 31, grp = tid >> 5;
  int w0 = grp * 12;
  float wgt[9];
#pragma unroll
  for (int t = 0; t < 9; ++t) wgt[t] = dww[t * 256 + cb + c];
  float bias = dwb[cb + c];

#pragma unroll
  for (int half = 0; half < 2; ++half) {
    float vals[2][12];
#pragma unroll
    for (int sub = 0; sub < 2; ++sub) {
      int orow = half * 2 + sub;
      float R[3][14];
#pragma unroll
      for (int rr = 0; rr < 3; ++rr) {
        const ushort_t* p = xs + ((orow + rr) * 32 + c) * 104;
        R[rr][0] = bf2f(p[3 + w0]);
        ushort4 q0 = *(const ushort4*)(p + 4 + w0);
        ushort4 q1 = *(const ushort4*)(p + 8 + w0);
        ushort4 q2 = *(const ushort4*)(p + 12 + w0);
        R[rr][1] = bf2f(q0.x);  R[rr][2] = bf2f(q0.y);
        R[rr][3] = bf2f(q0.z);  R[rr][4] = bf2f(q0.w);
        R[rr][5] = bf2f(q1.x);  R[rr][6] = bf2f(q1.y);
        R[rr][7] = bf2f(q1.z);  R[rr][8] = bf2f(q1.w);
        R[rr][9] = bf2f(q2.x);  R[rr][10] = bf2f(q2.y);
        R[rr][11] = bf2f(q2.z); R[rr][12] = bf2f(q2.w);
        R[rr][13] = bf2f(p[16 + w0]);
      }
#pragma unroll
      for (int k = 0; k < 12; ++k) {
        float acc = bias;
#pragma unroll
        for (int rr = 0; rr < 3; ++rr) {
          acc = fmaf(R[rr][k], wgt[rr * 3 + 0], acc);
          acc = fmaf(R[rr][k + 1], wgt[rr * 3 + 1], acc);
          acc = fmaf(R[rr][k + 2], wgt[rr * 3 + 2], acc);
        }
        vals[sub][k] = acc;
      }
    }
    if (half == 1) __syncthreads();  // protect ot from half-0 readers
#pragma unroll
    for (int sub = 0; sub < 2; ++sub)
#pragma unroll
      for (int k = 0; k < 12; ++k)
        ot[(sub * 96 + w0 + k) * 32 + c] = f2bf(vals[sub][k]);
    __syncthreads();
#pragma unroll
    for (int it = 0; it < 3; ++it) {
      int u = it * 256 + tid;
      int r2 = (u >= 384) ? 1 : 0;
      int rem = u - r2 * 384;
      int w = rem >> 2, cq = rem & 3;
      uint4 v = *(const uint4*)(ot + (r2 * 96 + w) * 32 + cq * 8);
      int h = h0 + half * 2 + r2;
      *(uint4*)(y + ((long)(n * 96 + h) * 96 + w) * 256 + cb + cq * 8) = v;
      *(uint4*)(yT + ((long)(n * 96 + w) * 96 + h) * 256 + cb + cq * 8) = v;
    }
  }
}

// ---------------- unified scan: gate GEMM + dwconv1d*sigmoid (streaming) ----
__global__ __launch_bounds__(512, 4) void k_scan(
    const ushort_t* __restrict__ src, const uint4* __restrict__ gp4,
    const float* __restrict__ dwaw, const float* __restrict__ dwab,
    const float* __restrict__ gab, const float* __restrict__ dwbw,
    const float* __restrict__ dwbb, const float* __restrict__ gbb,
    ushort_t* __restrict__ dst) {
  __shared__ __align__(16) char pool[34816];
  char* ylds = pool;            // 52 rows x 512B, swizzled (pixel q at row q-p0+2)
  char* olds = pool + 26624;    // 16 rows x 512B chunk, swizzled

  int tid = threadIdx.x;
  int bid = blockIdx.x;
  int seg = bid & 1, line = (bid >> 1) % 96, n = bid / 192;
  int p0 = seg * 48;
  long lbase = (long)(n * 96 + line) * 96;

  for (int u = tid; u < 52 * 32; u += 512) {
    int r = u >> 5, ks = u & 31;
    int q = p0 - 2 + r;
    uint4 v = make_uint4(0, 0, 0, 0);
    if (q >= 0 && q < 96)
      v = *(const uint4*)(src + (lbase + q) * 256 + ks * 8);
    *(uint4*)(ylds + r * 512 + ((ks * 16) ^ ((r & 7) << 4))) = v;
  }
  __syncthreads();

  int l = tid & 63, w = tid >> 6;
  int llo = l & 15, lhi = l >> 4;

  float part[3][2][4];

#pragma unroll
  for (int diri = 0; diri < 2; ++diri) {
    f32x4 acc[3][2];
#pragma unroll
    for (int mf = 0; mf < 3; ++mf)
#pragma unroll
      for (int ntl = 0; ntl < 2; ++ntl) acc[mf][ntl] = (f32x4){0.f, 0.f, 0.f, 0.f};

    const uint4* gbase = gp4 + ((long)(diri * 8) * 16 + w * 2) * 64 + l;
    short8x bc0 = *(const short8x*)(gbase);
    short8x bc1 = *(const short8x*)(gbase + 64);
#pragma unroll
    for (int kt = 0; kt < 8; ++kt) {
      short8x bn0, bn1;
      if (kt < 7) {
        bn0 = *(const short8x*)(gbase + (kt + 1) * 1024);
        bn1 = *(const short8x*)(gbase + (kt + 1) * 1024 + 64);
      }
      short8x a[3];
#pragma unroll
      for (int mf = 0; mf < 3; ++mf) {
        int arow = 2 + mf * 16 + llo;
        a[mf] = *(const short8x*)(ylds + arow * 512 +
                                  ((kt * 64 + lhi * 16) ^ ((arow & 7) << 4)));
      }
#pragma unroll
      for (int mf = 0; mf < 3; ++mf) {
        acc[mf][0] = __builtin_amdgcn_mfma_f32_16x16x32_bf16(a[mf], bc0, acc[mf][0], 0, 0, 0);
        acc[mf][1] = __builtin_amdgcn_mfma_f32_16x16x32_bf16(a[mf], bc1, acc[mf][1], 0, 0, 0);
      }
      bc0 = bn0;
      bc1 = bn1;
    }

    const float* dwv = diri ? dwbw : dwaw;
    const float* dbv = diri ? dwbb : dwab;
    const float* gbv = diri ? gbb : gab;
#pragma unroll
    for (int ntl = 0; ntl < 2; ++ntl) {
      int c = (w * 2 + ntl) * 16 + llo;
      float wt[5];
#pragma unroll
      for (int t = 0; t < 5; ++t)
        wt[t] = diri ? dwv[(4 - t) * 256 + c] : dwv[t * 256 + c];
      float cb = dbv[c], gb = gbv[c];
#pragma unroll
      for (int mf = 0; mf < 3; ++mf) {
        int pbase = mf * 16 + lhi * 4;
        float yv[8];
#pragma unroll
        for (int t = 0; t < 8; ++t) {
          int ry = pbase + t;
          yv[t] = bf2f(*(const ushort_t*)(ylds + ry * 512 +
                                          ((c * 2) ^ ((ry & 7) << 4))));
        }
#pragma unroll
        for (int r = 0; r < 4; ++r) {
          float conv = cb;
#pragma unroll
          for (int t = 0; t < 5; ++t) conv = fmaf(yv[r + t], wt[t], conv);
          float val = conv * sigf(acc[mf][ntl][r] + gb);
          if (diri == 0) part[mf][ntl][r] = val;
          else           part[mf][ntl][r] += val;
        }
      }
    }
  }

  // 3-pass chunked streaming output (16 rows each), no RMW
#pragma unroll
  for (int mf = 0; mf < 3; ++mf) {
    __syncthreads();
#pragma unroll
    for (int ntl = 0; ntl < 2; ++ntl) {
      int c = (w * 2 + ntl) * 16 + llo;
#pragma unroll
      for (int r = 0; r < 4; ++r) {
        int p = lhi * 4 + r;
        *(ushort_t*)(olds + p * 512 + ((c * 2) ^ ((p & 7) << 4))) =
            f2bf(part[mf][ntl][r]);
      }
    }
    __syncthreads();
    {
      int p = tid >> 5, ks = tid & 31;
      uint4 v = *(const uint4*)(olds + p * 512 + ((ks * 16) ^ ((p & 7) << 4)));
      *(uint4*)(dst + (lbase + p0 + mf * 16 + p) * 256 + ks * 8) = v;
    }
  }
}

// ---------------- fuse GEMM + residual: out(NCHW) = x + (o+oT')@Ft + b -------
__global__ __launch_bounds__(512, 4) void k_fuse(
    const ushort_t* __restrict__ o, const ushort_t* __restrict__ oT,
    const ushort_t* __restrict__ Ftp, const float* __restrict__ fuseb,
    const float* __restrict__ x, float* __restrict__ out) {
  __shared__ __align__(16) char pool[24576];  // alds 48x512B; epi 16KB overlay

  int tid = threadIdx.x;
  int pix0 = blockIdx.x * 48;
  int n = pix0 / HWSZ, hw0 = pix0 % HWSZ;
  int h = hw0 / 96, w0 = hw0 % 96;

  for (int u = tid; u < 48 * 32; u += 512) {
    int r = u >> 5, ks = u & 31;
    uint4 va = *(const uint4*)(o + (long)(pix0 + r) * 256 + ks * 8);
    uint4 vb = *(const uint4*)(oT + ((long)(n * 96 + w0 + r) * 96 + h) * 256 + ks * 8);
    ushort_t* a8 = (ushort_t*)&va;
    ushort_t* b8 = (ushort_t*)&vb;
#pragma unroll
    for (int j = 0; j < 8; ++j) a8[j] = f2bf(bf2f(a8[j]) + bf2f(b8[j]));
    *(uint4*)(pool + r * 512 + ((ks * 16) ^ ((r & 7) << 4))) = va;
  }
  __syncthreads();

  int l = tid & 63, w = tid >> 6;
  int llo = l & 15, lhi = l >> 4;

  const uint4* fp4 = (const uint4*)Ftp;
  f32x4 acc[3][2];
#pragma unroll
  for (int mf = 0; mf < 3; ++mf)
#pragma unroll
    for (int ntl = 0; ntl < 2; ++ntl) acc[mf][ntl] = (f32x4){0.f, 0.f, 0.f, 0.f};

  const uint4* fbase = fp4 + (long)(w * 2) * 64 + l;
  short8x bc0 = *(const short8x*)(fbase);
  short8x bc1 = *(const short8x*)(fbase + 64);
#pragma unroll
  for (int kt = 0; kt < 8; ++kt) {
    short8x bn0, bn1;
    if (kt < 7) {
      bn0 = *(const short8x*)(fbase + (kt + 1) * 1024);
      bn1 = *(const short8x*)(fbase + (kt + 1) * 1024 + 64);
    }
    short8x a[3];
#pragma unroll
    for (int mf = 0; mf < 3; ++mf) {
      int arow = mf * 16 + llo;
      a[mf] = *(const short8x*)(pool + arow * 512 +
                                ((kt * 64 + lhi * 16) ^ ((arow & 7) << 4)));
    }
#pragma unroll
    for (int mf = 0; mf < 3; ++mf) {
      acc[mf][0] = __builtin_amdgcn_mfma_f32_16x16x32_bf16(a[mf], bc0, acc[mf][0], 0, 0, 0);
      acc[mf][1] = __builtin_amdgcn_mfma_f32_16x16x32_bf16(a[mf], bc1, acc[mf][1], 0, 0, 0);
    }
    bc0 = bn0;
    bc1 = bn1;
  }

  // epilogue: 3 passes of 16 rows (pass = mf), pool reused as f32 swz32 buffer
#pragma unroll
  for (int mf = 0; mf < 3; ++mf) {
    __syncthreads();
#pragma unroll
    for (int ntl = 0; ntl < 2; ++ntl) {
      int c = (w * 2 + ntl) * 16 + llo;
      float fb = fuseb[c];
#pragma unroll
      for (int r = 0; r < 4; ++r) {
        int p = lhi * 4 + r;
        *(float*)(pool + swz32(p, c)) = acc[mf][ntl][r] + fb;
      }
    }
    __syncthreads();
    for (int i = tid; i < 4096; i += 512) {
      int c = i >> 4, p = i & 15;
      long addr = (long)(n * 256 + c) * HWSZ + hw0 + mf * 16 + p;
      out[addr] = x[addr] + *(const float*)(pool + swz32(p, c));
    }
  }
}

// ---------------- k_ff1: ln2 + GEMM1 + GLU -> u (r4-packed bf16), M=96 -------
// u layout: u[(row>>2)][col512][row&3] bf16 -> lane's 4 MFMA rows = one uint2.
__global__ __launch_bounds__(512, 4) void k_ff1(
    const float* __restrict__ xres, const float* __restrict__ mean2,
    const float* __restrict__ rstd2, const float* __restrict__ ln2w,
    const float* __restrict__ ln2b, const ushort_t* __restrict__ W1p,
    const float* __restrict__ ff1b, ushort_t* __restrict__ u) {
  __shared__ char hA[96 * 512];   // 48KB, XOR-swizzled
  __shared__ float sc[256], sh[256];

  int tid = threadIdx.x;
  int pix0 = blockIdx.x * 96;
  int n = pix0 / HWSZ, hw0 = pix0 % HWSZ;

  if (tid < 256) {
    int nc = n * 256 + tid;
    float scale = rstd2[nc] * ln2w[tid];
    sc[tid] = scale;
    sh[tid] = ln2b[tid] - mean2[nc] * scale;
  }
  __syncthreads();

  // staging: 2 channels x 2 pixels per iteration, packed uint LDS stores
  for (int i = tid; i < 6144; i += 512) {
    int cp = i / 48, pp = i % 48;
    int c0 = cp * 2;
    long base0 = (long)(n * 256 + c0) * HWSZ + hw0 + pp * 2;
    float2 v0 = *(const float2*)(xres + base0);
    float2 v1 = *(const float2*)(xres + base0 + HWSZ);
    float s0 = sc[c0], h0 = sh[c0];
    float s1 = sc[c0 + 1], h1 = sh[c0 + 1];
    int p0 = pp * 2;
    uint_t w0 = (uint_t)f2bf(fmaf(v0.x, s0, h0)) |
                ((uint_t)f2bf(fmaf(v1.x, s1, h1)) << 16);
    uint_t w1 = (uint_t)f2bf(fmaf(v0.y, s0, h0)) |
                ((uint_t)f2bf(fmaf(v1.y, s1, h1)) << 16);
    *(uint_t*)(hA + p0 * 512 + ((c0 * 2) ^ ((p0 & 7) << 4))) = w0;
    *(uint_t*)(hA + (p0 + 1) * 512 + ((c0 * 2) ^ (((p0 + 1) & 7) << 4))) = w1;
  }
  __syncthreads();

  int l = tid & 63, w = tid >> 6;
  int llo = l & 15, lhi = l >> 4;

  const uint4* W1p4 = (const uint4*)W1p;   // [kt8][pb32][ag2][64] uint4
#pragma unroll
  for (int q = 0; q < 4; ++q) {
    int pb = q * 8 + w;
    f32x4 ca[6][2];
#pragma unroll
    for (int mf = 0; mf < 6; ++mf) {
      ca[mf][0] = (f32x4){0.f, 0.f, 0.f, 0.f};
      ca[mf][1] = (f32x4){0.f, 0.f, 0.f, 0.f};
    }
    const uint4* wb = W1p4 + (long)(pb * 2) * 64 + l;   // kt stride = 4096 uint4
    short8x bca = *(const short8x*)(wb);
    short8x bcg = *(const short8x*)(wb + 64);
#pragma unroll
    for (int kt = 0; kt < 8; ++kt) {
      short8x bna, bng;
      if (kt < 7) {
        bna = *(const short8x*)(wb + (kt + 1) * 4096);
        bng = *(const short8x*)(wb + (kt + 1) * 4096 + 64);
      }
      short8x a[6];
#pragma unroll
      for (int mf = 0; mf < 6; ++mf) {
        int arow = mf * 16 + llo;
        a[mf] = *(const short8x*)(hA + arow * 512 +
                                  ((kt * 64 + lhi * 16) ^ ((arow & 7) << 4)));
      }
#pragma unroll
      for (int mf = 0; mf < 6; ++mf) {
        ca[mf][0] = __builtin_amdgcn_mfma_f32_16x16x32_bf16(a[mf], bca, ca[mf][0], 0, 0, 0);
        ca[mf][1] = __builtin_amdgcn_mfma_f32_16x16x32_bf16(a[mf], bcg, ca[mf][1], 0, 0, 0);
      }
      bca = bna;
      bcg = bng;
    }
    // GLU -> r4-packed u: lane's 4 rows = one uint2 (coalesced 128B per lhi-group)
    int ucol = pb * 16 + llo;
    float ba = ff1b[ucol], bg = ff1b[512 + ucol];
    int rb0 = (pix0 >> 2) + lhi;
#pragma unroll
    for (int mf = 0; mf < 6; ++mf) {
      ushort_t b0 = f2bf((ca[mf][0][0] + ba) * sigf(ca[mf][1][0] + bg));
      ushort_t b1 = f2bf((ca[mf][0][1] + ba) * sigf(ca[mf][1][1] + bg));
      ushort_t b2 = f2bf((ca[mf][0][2] + ba) * sigf(ca[mf][1][2] + bg));
      ushort_t b3 = f2bf((ca[mf][0][3] + ba) * sigf(ca[mf][1][3] + bg));
      uint2 pk;
      pk.x = (uint_t)b0 | ((uint_t)b1 << 16);
      pk.y = (uint_t)b2 | ((uint_t)b3 << 16);
      *(uint2*)(u + ((long)(rb0 + mf * 4) * 512 + ucol) * 4) = pk;
    }
  }
}

// ---------------- k_ff2: GEMM2 (u @ W2) + bias + residual (out +=), M=96 ----
// u is r4-packed: u[(row>>2)][col512][row&3].
__global__ __launch_bounds__(512, 4) void k_ff2(
    const ushort_t* __restrict__ u, const ushort_t* __restrict__ W2p,
    const float* __restrict__ ff2b, float* __restrict__ out) {
  __shared__ __align__(16) char pool[24576];  // uA 96x256B chunk; epi overlay

  int tid = threadIdx.x;
  int pix0 = blockIdx.x * 96;
  int n = pix0 / HWSZ, hw0 = pix0 % HWSZ;
  int rb0 = pix0 >> 2;

  int l = tid & 63, w = tid >> 6;
  int llo = l & 15, lhi = l >> 4;

  const uint4* W2p4 = (const uint4*)W2p;   // [kt16][nt16][64] uint4

  f32x4 zacc[6][2];
#pragma unroll
  for (int mf = 0; mf < 6; ++mf) {
    zacc[mf][0] = (f32x4){0.f, 0.f, 0.f, 0.f};
    zacc[mf][1] = (f32x4){0.f, 0.f, 0.f, 0.f};
  }

#pragma unroll
  for (int kc = 0; kc < 4; ++kc) {
    __syncthreads();
    for (int i = tid; i < 3072; i += 512) {
      int col = i & 127, rbl = i >> 7;          // 24 rb-groups x 128 cols
      uint2 v = *(const uint2*)(u + ((long)(rb0 + rbl) * 512 + kc * 128 + col) * 4);
      ushort_t* b = (ushort_t*)&v;
      int p = rbl * 4;
#pragma unroll
      for (int k = 0; k < 4; ++k)
        *(ushort_t*)(pool + (p + k) * 256 + ((col * 2) ^ (((p + k) & 7) << 4))) = b[k];
    }
    __syncthreads();
#pragma unroll
    for (int ks = 0; ks < 4; ++ks) {
      int kt = kc * 4 + ks;
      short8x a[6];
#pragma unroll
      for (int mf = 0; mf < 6; ++mf) {
        int arow = mf * 16 + llo;
        a[mf] = *(const short8x*)(pool + arow * 256 +
                                  ((ks * 64 + lhi * 16) ^ ((arow & 7) << 4)));
      }
      short8x b0 = *(const short8x*)(W2p4 + (long)(kt * 16 + w * 2) * 64 + l);
      short8x b1 = *(const short8x*)(W2p4 + (long)(kt * 16 + w * 2 + 1) * 64 + l);
#pragma unroll
      for (int mf = 0; mf < 6; ++mf) {
        zacc[mf][0] = __builtin_amdgcn_mfma_f32_16x16x32_bf16(a[mf], b0, zacc[mf][0], 0, 0, 0);
        zacc[mf][1] = __builtin_amdgcn_mfma_f32_16x16x32_bf16(a[mf], b1, zacc[mf][1], 0, 0, 0);
      }
    }
  }

  // epilogue: 6 passes of 16 rows, pool reused as f32 swz32 buffer
#pragma unroll
  for (int mf = 0; mf < 6; ++mf) {
    __syncthreads();
#pragma unroll
    for (int ntl = 0; ntl < 2; ++ntl) {
      int c = (w * 2 + ntl) * 16 + llo;
      float fb = ff2b[c];
#pragma unroll
      for (int r = 0; r < 4; ++r) {
        int p = lhi * 4 + r;
        *(float*)(pool + swz32(p, c)) = zacc[mf][ntl][r] + fb;
      }
    }
    __syncthreads();
    for (int i = tid; i < 4096; i += 512) {
      int c = i >> 4, p = i & 15;
      long addr = (long)(n * 256 + c) * HWSZ + hw0 + mf * 16 + p;
      out[addr] += *(const float*)(pool + swz32(p, c));
    }
  }
}

extern "C" void kernel_launch(void* const* d_in, const int* in_sizes, int n_in,
                              void* d_out, int out_size, void* d_ws, size_t ws_size,
                              hipStream_t stream) {
  (void)in_sizes; (void)n_in; (void)out_size; (void)ws_size;
  const float* x     = (const float*)d_in[0];
  const float* ln1w  = (const float*)d_in[1];
  const float* ln1b  = (const float*)d_in[2];
  const float* dww   = (const float*)d_in[3];
  const float* dwb   = (const float*)d_in[4];
  const float* lr_w  = (const float*)d_in[5];
  const float* lr_b  = (const float*)d_in[6];
  const float* lr_gw = (const float*)d_in[7];
  const float* lr_gb = (const float*)d_in[8];
  const float* rl_w  = (const float*)d_in[9];
  const float* rl_b  = (const float*)d_in[10];
  const float* rl_gw = (const float*)d_in[11];
  const float* rl_gb = (const float*)d_in[12];
  const float* tb_w  = (const float*)d_in[13];
  const float* tb_b  = (const float*)d_in[14];
  const float* tb_gw = (const float*)d_in[15];
  const float* tb_gb = (const float*)d_in[16];
  const float* bt_w  = (const float*)d_in[17];
  const float* bt_b  = (const float*)d_in[18];
  const float* bt_gw = (const float*)d_in[19];
  const float* bt_gb = (const float*)d_in[20];
  const float* fusew = (const float*)d_in[21];
  const float* fuseb = (const float*)d_in[22];
  const float* ln2w  = (const float*)d_in[23];
  const float* ln2b  = (const float*)d_in[24];
  const float* ff1w  = (const float*)d_in[25];
  const float* ff1b  = (const float*)d_in[26];
  const float* ff2w  = (const float*)d_in[27];
  const float* ff2b  = (const float*)d_in[28];

  float* out = (float*)d_out;
  ushort_t* y  = (ushort_t*)d_ws;                 // 18874368 bf16
  ushort_t* yT = y + 18874368;                    // 18874368 bf16
  ushort_t* o  = yT + 18874368;                   // 18874368 bf16
  ushort_t* oT = o + 18874368;                    // 18874368 bf16
  ushort_t* uu = y;                               // aliases y+yT (dead by k_ff1)
  float* mean1 = (float*)(oT + 18874368);
  float* rstd1 = mean1 + 2048;
  float* mean2 = rstd1 + 2048;
  float* rstd2 = mean2 + 2048;
  ushort_t* Gp  = (ushort_t*)(rstd2 + 2048);      // 262144
  ushort_t* Ftp = Gp + 262144;                    // 65536
  ushort_t* W1p = Ftp + 65536;                    // 262144
  ushort_t* W2p = W1p + 262144;                   // 131072

  k_pack<<<2816, TPB, 0, stream>>>(lr_gw, rl_gw, tb_gw, bt_gw, fusew, ff1w, ff2w,
                                   Gp, Ftp, W1p, W2p);
  k_stats<<<2048, TPB, 0, stream>>>(x, mean1, rstd1);
  k_lndw<<<1536, TPB, 0, stream>>>(x, mean1, rstd1, ln1w, ln1b, dww, dwb, y, yT);
  k_scan<<<1536, 512, 0, stream>>>(y, (const uint4*)Gp,
                                   lr_w, lr_b, lr_gb, rl_w, rl_b, rl_gb, o);
  k_scan<<<1536, 512, 0, stream>>>(yT, (const uint4*)(Gp + 131072),
                                   tb_w, tb_b, tb_gb, bt_w, bt_b, bt_gb, oT);
  k_fuse<<<1536, 512, 0, stream>>>(o, oT, Ftp, fuseb, x, out);
  k_stats<<<2048, TPB, 0, stream>>>(out, mean2, rstd2);
  k_ff1<<<768, 512, 0, stream>>>(out, mean2, rstd2, ln2w, ln2b, W1p, ff1b, uu);
  k_ff2<<<768, 512, 0, stream>>>(uu, W2p, ff2b, out);
}

// Round 13
// 318.550 us; speedup vs baseline: 1.0893x; 1.0893x over previous
//
#include <hip/hip_runtime.h>

#define TPB 256
#define HWSZ 9216      // 96*96

typedef __attribute__((ext_vector_type(8))) short short8x;
typedef __attribute__((ext_vector_type(4))) float f32x4;
typedef unsigned short ushort_t;
typedef unsigned int uint_t;

__device__ __forceinline__ float sigf(float v) { return 1.0f / (1.0f + __expf(-v)); }

__device__ __forceinline__ ushort_t f2bf(float f) {
  uint_t u = __float_as_uint(f);
  u = (u + 0x7fffu + ((u >> 16) & 1u)) >> 16;
  return (ushort_t)u;
}
__device__ __forceinline__ float bf2f(ushort_t h) {
  return __uint_as_float(((uint_t)h) << 16);
}

// ---------------- pack weights to fragment-major bf16 ----------------
// 16x16x32 B-frag tile(kt,nt): elem(l,j) = B[kt*32+(l>>4)*8+j][nt*16+(l&15)]
// Gp:  [dir4][kt8][nt16][64][8]
// Ftp: [kt8][nt16][64][8]
// W1p: [kt8][pb32][ag2][64][8]  (pair-block pb = u-cols pb*16..+15; ag=0 a, 1 g)
// W2p: [kt16][nt16][64][8]
__global__ __launch_bounds__(TPB) void k_pack(
    const float* __restrict__ lrg, const float* __restrict__ rlg,
    const float* __restrict__ tbg, const float* __restrict__ btg,
    const float* __restrict__ fusew, const float* __restrict__ ff1w,
    const float* __restrict__ ff2w,
    ushort_t* __restrict__ Gp, ushort_t* __restrict__ Ftp,
    ushort_t* __restrict__ W1p, ushort_t* __restrict__ W2p) {
  int i = blockIdx.x * TPB + threadIdx.x;
  if (i < 262144) {
    int d = i >> 16, r = i & 65535;
    int kt = r >> 13, nt = (r >> 9) & 15, l = (r >> 3) & 63, j = r & 7;
    int k = kt * 32 + (l >> 4) * 8 + j;
    int n_ = nt * 16 + (l & 15);
    const float* g = (d == 0) ? lrg : (d == 1) ? rlg : (d == 2) ? tbg : btg;
    Gp[i] = f2bf(g[n_ * 256 + k]);
  } else if (i < 327680) {
    int r = i - 262144;
    int kt = r >> 13, nt = (r >> 9) & 15, l = (r >> 3) & 63, j = r & 7;
    int k = kt * 32 + (l >> 4) * 8 + j;
    int n_ = nt * 16 + (l & 15);
    Ftp[r] = f2bf(fusew[n_ * 256 + k]);
  } else if (i < 589824) {
    int r = i - 327680;
    int kt = r >> 15, pb = (r >> 10) & 31, ag = (r >> 9) & 1;
    int l = (r >> 3) & 63, j = r & 7;
    int k = kt * 32 + (l >> 4) * 8 + j;
    int colb = pb * 16 + (l & 15);
    int col = ag ? (512 + colb) : colb;
    W1p[r] = f2bf(ff1w[col * 256 + k]);
  } else if (i < 720896) {
    int r = i - 589824;
    int kt = r >> 13, nt = (r >> 9) & 15, l = (r >> 3) & 63, j = r & 7;
    int k = kt * 32 + (l >> 4) * 8 + j;
    int n_ = nt * 16 + (l & 15);
    W2p[r] = f2bf(ff2w[n_ * 512 + k]);
  }
}

// ---------------- per-(n,c) LayerNorm2d stats (float4) ----------------
__global__ __launch_bounds__(TPB) void k_stats(const float* __restrict__ src,
                                               float* __restrict__ mean,
                                               float* __restrict__ rstd) {
  int nc = blockIdx.x;
  const float4* p = (const float4*)(src + (long)nc * HWSZ);
  float s = 0.f, s2 = 0.f;
  for (int i = threadIdx.x; i < 2304; i += TPB) {
    float4 v = p[i];
    s += (v.x + v.y) + (v.z + v.w);
    s2 = fmaf(v.x, v.x, fmaf(v.y, v.y, fmaf(v.z, v.z, fmaf(v.w, v.w, s2))));
  }
#pragma unroll
  for (int off = 32; off > 0; off >>= 1) {
    s += __shfl_down(s, off);
    s2 += __shfl_down(s2, off);
  }
  __shared__ float ls[4], ls2[4];
  int lane = threadIdx.x & 63, wv = threadIdx.x >> 6;
  if (lane == 0) { ls[wv] = s; ls2[wv] = s2; }
  __syncthreads();
  if (threadIdx.x == 0) {
    float S = ls[0] + ls[1] + ls[2] + ls[3];
    float S2 = ls2[0] + ls2[1] + ls2[2] + ls2[3];
    float m = S * (1.0f / HWSZ);
    float var = S2 * (1.0f / HWSZ) - m * m;
    mean[nc] = m;
    rstd[nc] = rsqrtf(fmaxf(var, 0.f) + 1e-6f);
  }
}

// ---------------- ln1 + depthwise 3x3 -> y (NHWC) and yT (transposed) -------
// Block = (n, 4-row band, 32-ch group). Grid 8*24*8 = 1536.
__global__ __launch_bounds__(TPB) void k_lndw(
    const float* __restrict__ x, const float* __restrict__ mean1,
    const float* __restrict__ rstd1, const float* __restrict__ ln1w,
    const float* __restrict__ ln1b, const float* __restrict__ dww,
    const float* __restrict__ dwb, ushort_t* __restrict__ y,
    ushort_t* __restrict__ yT) {
  __shared__ __align__(16) ushort_t xs[6 * 32 * 104];   // 39936 B
  __shared__ __align__(16) ushort_t ot[2 * 96 * 32];    // 12288 B
  __shared__ float sc[32], sh[32];

  int tid = threadIdx.x;
  int bid = blockIdx.x;
  int cb = (bid & 7) * 32;
  int hb = (bid >> 3) % 24;
  int n  = bid / 192;
  int h0 = hb * 4;

  if (tid < 32) {
    int c = cb + tid;
    int nc = n * 256 + c;
    float scale = rstd1[nc] * ln1w[c];
    sc[tid] = scale;
    sh[tid] = ln1b[c] - mean1[nc] * scale;
  }
  if (tid < 192) {   // w halos
    xs[tid * 104 + 3] = 0;
    xs[tid * 104 + 100] = 0;
  }
  __syncthreads();

  // stage 6 LN'd rows (h0-1 .. h0+4), float4 loads -> bf16x4 stores
  for (int i = tid; i < 4608; i += TPB) {
    int rc = i / 24;            // 0..191  (row*32 + c)
    int f4 = i - rc * 24;       // 0..23
    int row = rc >> 5, c = rc & 31;
    int hh = h0 - 1 + row;
    uint2 pk = make_uint2(0, 0);
    if (hh >= 0 && hh < 96) {
      float4 v = *(const float4*)(x + (long)(n * 256 + cb + c) * HWSZ +
                                  hh * 96 + f4 * 4);
      float scale = sc[c], shift = sh[c];
      ushort_t p0 = f2bf(fmaf(v.x, scale, shift));
      ushort_t p1 = f2bf(fmaf(v.y, scale, shift));
      ushort_t p2 = f2bf(fmaf(v.z, scale, shift));
      ushort_t p3 = f2bf(fmaf(v.w, scale, shift));
      pk.x = (uint_t)p0 | ((uint_t)p1 << 16);
      pk.y = (uint_t)p2 | ((uint_t)p3 << 16);
    }
    *(uint2*)(xs + rc * 104 + 4 + f4 * 4) = pk;
  }
  __syncthreads();

  // conv: thread = (c = tid&31, 12-w group grp = tid>>5)
  int c = tid & 31, grp = tid >> 5;
  int w0 = grp * 12;
  float wgt[9];
#pragma unroll
  for (int t = 0; t < 9; ++t) wgt[t] = dww[t * 256 + cb + c];
  float bias = dwb[cb + c];

#pragma unroll
  for (int half = 0; half < 2; ++half) {
    float vals[2][12];
#pragma unroll
    for (int sub = 0; sub < 2; ++sub) {
      int orow = half * 2 + sub;
      float R[3][14];
#pragma unroll
      for (int rr = 0; rr < 3; ++rr) {
        const ushort_t* p = xs + ((orow + rr) * 32 + c) * 104;
        R[rr][0] = bf2f(p[3 + w0]);
        ushort4 q0 = *(const ushort4*)(p + 4 + w0);
        ushort4 q1 = *(const ushort4*)(p + 8 + w0);
        ushort4 q2 = *(const ushort4*)(p + 12 + w0);
        R[rr][1] = bf2f(q0.x);  R[rr][2] = bf2f(q0.y);
        R[rr][3] = bf2f(q0.z);  R[rr][4] = bf2f(q0.w);
        R[rr][5] = bf2f(q1.x);  R[rr][6] = bf2f(q1.y);
        R[rr][7] = bf2f(q1.z);  R[rr][8] = bf2f(q1.w);
        R[rr][9] = bf2f(q2.x);  R[rr][10] = bf2f(q2.y);
        R[rr][11] = bf2f(q2.z); R[rr][12] = bf2f(q2.w);
        R[rr][13] = bf2f(p[16 + w0]);
      }
#pragma unroll
      for (int k = 0; k < 12; ++k) {
        float acc = bias;
#pragma unroll
        for (int rr = 0; rr < 3; ++rr) {
          acc = fmaf(R[rr][k], wgt[rr * 3 + 0], acc);
          acc = fmaf(R[rr][k + 1], wgt[rr * 3 + 1], acc);
          acc = fmaf(R[rr][k + 2], wgt[rr * 3 + 2], acc);
        }
        vals[sub][k] = acc;
      }
    }
    if (half == 1) __syncthreads();  // protect ot from half-0 readers
#pragma unroll
    for (int sub = 0; sub < 2; ++sub)
#pragma unroll
      for (int k = 0; k < 12; ++k)
        ot[(sub * 96 + w0 + k) * 32 + c] = f2bf(vals[sub][k]);
    __syncthreads();
#pragma unroll
    for (int it = 0; it < 3; ++it) {
      int u = it * 256 + tid;
      int r2 = (u >= 384) ? 1 : 0;
      int rem = u - r2 * 384;
      int w = rem >> 2, cq = rem & 3;
      uint4 v = *(const uint4*)(ot + (r2 * 96 + w) * 32 + cq * 8);
      int h = h0 + half * 2 + r2;
      *(uint4*)(y + ((long)(n * 96 + h) * 96 + w) * 256 + cb + cq * 8) = v;
      *(uint4*)(yT + ((long)(n * 96 + w) * 96 + h) * 256 + cb + cq * 8) = v;
    }
  }
}

// ---------------- unified scan: gate GEMM + dwconv1d*sigmoid (streaming) ----
__global__ __launch_bounds__(512, 4) void k_scan(
    const ushort_t* __restrict__ src, const uint4* __restrict__ gp4,
    const float* __restrict__ dwaw, const float* __restrict__ dwab,
    const float* __restrict__ gab, const float* __restrict__ dwbw,
    const float* __restrict__ dwbb, const float* __restrict__ gbb,
    ushort_t* __restrict__ dst) {
  __shared__ __align__(16) char pool[34816];
  char* ylds = pool;            // 52 rows x 512B, swizzled (pixel q at row q-p0+2)
  char* olds = pool + 26624;    // 16 rows x 512B chunk, swizzled

  int tid = threadIdx.x;
  int bid = blockIdx.x;
  int seg = bid & 1, line = (bid >> 1) % 96, n = bid / 192;
  int p0 = seg * 48;
  long lbase = (long)(n * 96 + line) * 96;

  for (int u = tid; u < 52 * 32; u += 512) {
    int r = u >> 5, ks = u & 31;
    int q = p0 - 2 + r;
    uint4 v = make_uint4(0, 0, 0, 0);
    if (q >= 0 && q < 96)
      v = *(const uint4*)(src + (lbase + q) * 256 + ks * 8);
    *(uint4*)(ylds + r * 512 + ((ks * 16) ^ ((r & 7) << 4))) = v;
  }
  __syncthreads();

  int l = tid & 63, w = tid >> 6;
  int llo = l & 15, lhi = l >> 4;

  float part[3][2][4];

#pragma unroll
  for (int diri = 0; diri < 2; ++diri) {
    f32x4 acc[3][2];
#pragma unroll
    for (int mf = 0; mf < 3; ++mf)
#pragma unroll
      for (int ntl = 0; ntl < 2; ++ntl) acc[mf][ntl] = (f32x4){0.f, 0.f, 0.f, 0.f};

    const uint4* gbase = gp4 + ((long)(diri * 8) * 16 + w * 2) * 64 + l;
    short8x bc0 = *(const short8x*)(gbase);
    short8x bc1 = *(const short8x*)(gbase + 64);
#pragma unroll
    for (int kt = 0; kt < 8; ++kt) {
      short8x bn0, bn1;
      if (kt < 7) {
        bn0 = *(const short8x*)(gbase + (kt + 1) * 1024);
        bn1 = *(const short8x*)(gbase + (kt + 1) * 1024 + 64);
      }
      short8x a[3];
#pragma unroll
      for (int mf = 0; mf < 3; ++mf) {
        int arow = 2 + mf * 16 + llo;
        a[mf] = *(const short8x*)(ylds + arow * 512 +
                                  ((kt * 64 + lhi * 16) ^ ((arow & 7) << 4)));
      }
#pragma unroll
      for (int mf = 0; mf < 3; ++mf) {
        acc[mf][0] = __builtin_amdgcn_mfma_f32_16x16x32_bf16(a[mf], bc0, acc[mf][0], 0, 0, 0);
        acc[mf][1] = __builtin_amdgcn_mfma_f32_16x16x32_bf16(a[mf], bc1, acc[mf][1], 0, 0, 0);
      }
      bc0 = bn0;
      bc1 = bn1;
    }

    const float* dwv = diri ? dwbw : dwaw;
    const float* dbv = diri ? dwbb : dwab;
    const float* gbv = diri ? gbb : gab;
#pragma unroll
    for (int ntl = 0; ntl < 2; ++ntl) {
      int c = (w * 2 + ntl) * 16 + llo;
      float wt[5];
#pragma unroll
      for (int t = 0; t < 5; ++t)
        wt[t] = diri ? dwv[(4 - t) * 256 + c] : dwv[t * 256 + c];
      float cb = dbv[c], gb = gbv[c];
#pragma unroll
      for (int mf = 0; mf < 3; ++mf) {
        int pbase = mf * 16 + lhi * 4;
        float yv[8];
#pragma unroll
        for (int t = 0; t < 8; ++t) {
          int ry = pbase + t;
          yv[t] = bf2f(*(const ushort_t*)(ylds + ry * 512 +
                                          ((c * 2) ^ ((ry & 7) << 4))));
        }
#pragma unroll
        for (int r = 0; r < 4; ++r) {
          float conv = cb;
#pragma unroll
          for (int t = 0; t < 5; ++t) conv = fmaf(yv[r + t], wt[t], conv);
          float val = conv * sigf(acc[mf][ntl][r] + gb);
          if (diri == 0) part[mf][ntl][r] = val;
          else           part[mf][ntl][r] += val;
        }
      }
    }
  }

  // 3-pass chunked streaming output (16 rows each), no RMW
#pragma unroll
  for (int mf = 0; mf < 3; ++mf) {
    __syncthreads();
#pragma unroll
    for (int ntl = 0; ntl < 2; ++ntl) {
      int c = (w * 2 + ntl) * 16 + llo;
#pragma unroll
      for (int r = 0; r < 4; ++r) {
        int p = lhi * 4 + r;
        *(ushort_t*)(olds + p * 512 + ((c * 2) ^ ((p & 7) << 4))) =
            f2bf(part[mf][ntl][r]);
      }
    }
    __syncthreads();
    {
      int p = tid >> 5, ks = tid & 31;
      uint4 v = *(const uint4*)(olds + p * 512 + ((ks * 16) ^ ((p & 7) << 4)));
      *(uint4*)(dst + (lbase + p0 + mf * 16 + p) * 256 + ks * 8) = v;
    }
  }
}

// ---------------- fuse GEMM + residual: out(NCHW) = x + (o+oT')@Ft + b -------
// M=48/block, 8 waves, wave w owns nt {w*2, w*2+1}; mf=3.
// Direct float4 epilogue (lane's 4 MFMA rows = 4 consecutive pixels).
__global__ __launch_bounds__(512, 4) void k_fuse(
    const ushort_t* __restrict__ o, const ushort_t* __restrict__ oT,
    const ushort_t* __restrict__ Ftp, const float* __restrict__ fuseb,
    const float* __restrict__ x, float* __restrict__ out) {
  __shared__ __align__(16) char pool[24576];  // alds 48x512B

  int tid = threadIdx.x;
  int pix0 = blockIdx.x * 48;
  int n = pix0 / HWSZ, hw0 = pix0 % HWSZ;
  int h = hw0 / 96, w0 = hw0 % 96;

  for (int u = tid; u < 48 * 32; u += 512) {
    int r = u >> 5, ks = u & 31;
    uint4 va = *(const uint4*)(o + (long)(pix0 + r) * 256 + ks * 8);
    uint4 vb = *(const uint4*)(oT + ((long)(n * 96 + w0 + r) * 96 + h) * 256 + ks * 8);
    ushort_t* a8 = (ushort_t*)&va;
    ushort_t* b8 = (ushort_t*)&vb;
#pragma unroll
    for (int j = 0; j < 8; ++j) a8[j] = f2bf(bf2f(a8[j]) + bf2f(b8[j]));
    *(uint4*)(pool + r * 512 + ((ks * 16) ^ ((r & 7) << 4))) = va;
  }
  __syncthreads();

  int l = tid & 63, w = tid >> 6;
  int llo = l & 15, lhi = l >> 4;

  const uint4* fp4 = (const uint4*)Ftp;
  f32x4 acc[3][2];
#pragma unroll
  for (int mf = 0; mf < 3; ++mf)
#pragma unroll
    for (int ntl = 0; ntl < 2; ++ntl) acc[mf][ntl] = (f32x4){0.f, 0.f, 0.f, 0.f};

  const uint4* fbase = fp4 + (long)(w * 2) * 64 + l;
  short8x bc0 = *(const short8x*)(fbase);
  short8x bc1 = *(const short8x*)(fbase + 64);
#pragma unroll
  for (int kt = 0; kt < 8; ++kt) {
    short8x bn0, bn1;
    if (kt < 7) {
      bn0 = *(const short8x*)(fbase + (kt + 1) * 1024);
      bn1 = *(const short8x*)(fbase + (kt + 1) * 1024 + 64);
    }
    short8x a[3];
#pragma unroll
    for (int mf = 0; mf < 3; ++mf) {
      int arow = mf * 16 + llo;
      a[mf] = *(const short8x*)(pool + arow * 512 +
                                ((kt * 64 + lhi * 16) ^ ((arow & 7) << 4)));
    }
#pragma unroll
    for (int mf = 0; mf < 3; ++mf) {
      acc[mf][0] = __builtin_amdgcn_mfma_f32_16x16x32_bf16(a[mf], bc0, acc[mf][0], 0, 0, 0);
      acc[mf][1] = __builtin_amdgcn_mfma_f32_16x16x32_bf16(a[mf], bc1, acc[mf][1], 0, 0, 0);
    }
    bc0 = bn0;
    bc1 = bn1;
  }

  // direct epilogue: lane (mf,ntl) owns pixels hw0+mf*16+lhi*4..+3 at channel c
#pragma unroll
  for (int mf = 0; mf < 3; ++mf)
#pragma unroll
    for (int ntl = 0; ntl < 2; ++ntl) {
      int c = (w * 2 + ntl) * 16 + llo;
      float fb = fuseb[c];
      long addr = (long)(n * 256 + c) * HWSZ + hw0 + mf * 16 + lhi * 4;
      float4 xv = *(const float4*)(x + addr);
      float4 ov;
      ov.x = xv.x + acc[mf][ntl][0] + fb;
      ov.y = xv.y + acc[mf][ntl][1] + fb;
      ov.z = xv.z + acc[mf][ntl][2] + fb;
      ov.w = xv.w + acc[mf][ntl][3] + fb;
      *(float4*)(out + addr) = ov;
    }
}

// ---------------- k_ff1: ln2 + GEMM1 + GLU -> u (r4-packed bf16), M=96 -------
// u layout: u[(row>>2)][col512][row&3] bf16 -> lane's 4 MFMA rows = one uint2.
__global__ __launch_bounds__(512, 4) void k_ff1(
    const float* __restrict__ xres, const float* __restrict__ mean2,
    const float* __restrict__ rstd2, const float* __restrict__ ln2w,
    const float* __restrict__ ln2b, const ushort_t* __restrict__ W1p,
    const float* __restrict__ ff1b, ushort_t* __restrict__ u) {
  __shared__ char hA[96 * 512];   // 48KB, XOR-swizzled
  __shared__ float sc[256], sh[256];

  int tid = threadIdx.x;
  int pix0 = blockIdx.x * 96;
  int n = pix0 / HWSZ, hw0 = pix0 % HWSZ;

  if (tid < 256) {
    int nc = n * 256 + tid;
    float scale = rstd2[nc] * ln2w[tid];
    sc[tid] = scale;
    sh[tid] = ln2b[tid] - mean2[nc] * scale;
  }
  __syncthreads();

  // staging: 2 channels x 2 pixels per iteration, packed uint LDS stores
  for (int i = tid; i < 6144; i += 512) {
    int cp = i / 48, pp = i % 48;
    int c0 = cp * 2;
    long base0 = (long)(n * 256 + c0) * HWSZ + hw0 + pp * 2;
    float2 v0 = *(const float2*)(xres + base0);
    float2 v1 = *(const float2*)(xres + base0 + HWSZ);
    float s0 = sc[c0], h0 = sh[c0];
    float s1 = sc[c0 + 1], h1 = sh[c0 + 1];
    int p0 = pp * 2;
    uint_t w0 = (uint_t)f2bf(fmaf(v0.x, s0, h0)) |
                ((uint_t)f2bf(fmaf(v1.x, s1, h1)) << 16);
    uint_t w1 = (uint_t)f2bf(fmaf(v0.y, s0, h0)) |
                ((uint_t)f2bf(fmaf(v1.y, s1, h1)) << 16);
    *(uint_t*)(hA + p0 * 512 + ((c0 * 2) ^ ((p0 & 7) << 4))) = w0;
    *(uint_t*)(hA + (p0 + 1) * 512 + ((c0 * 2) ^ (((p0 + 1) & 7) << 4))) = w1;
  }
  __syncthreads();

  int l = tid & 63, w = tid >> 6;
  int llo = l & 15, lhi = l >> 4;

  const uint4* W1p4 = (const uint4*)W1p;   // [kt8][pb32][ag2][64] uint4
#pragma unroll
  for (int q = 0; q < 4; ++q) {
    int pb = q * 8 + w;
    f32x4 ca[6][2];
#pragma unroll
    for (int mf = 0; mf < 6; ++mf) {
      ca[mf][0] = (f32x4){0.f, 0.f, 0.f, 0.f};
      ca[mf][1] = (f32x4){0.f, 0.f, 0.f, 0.f};
    }
    const uint4* wb = W1p4 + (long)(pb * 2) * 64 + l;   // kt stride = 4096 uint4
    short8x bca = *(const short8x*)(wb);
    short8x bcg = *(const short8x*)(wb + 64);
#pragma unroll
    for (int kt = 0; kt < 8; ++kt) {
      short8x bna, bng;
      if (kt < 7) {
        bna = *(const short8x*)(wb + (kt + 1) * 4096);
        bng = *(const short8x*)(wb + (kt + 1) * 4096 + 64);
      }
      short8x a[6];
#pragma unroll
      for (int mf = 0; mf < 6; ++mf) {
        int arow = mf * 16 + llo;
        a[mf] = *(const short8x*)(hA + arow * 512 +
                                  ((kt * 64 + lhi * 16) ^ ((arow & 7) << 4)));
      }
#pragma unroll
      for (int mf = 0; mf < 6; ++mf) {
        ca[mf][0] = __builtin_amdgcn_mfma_f32_16x16x32_bf16(a[mf], bca, ca[mf][0], 0, 0, 0);
        ca[mf][1] = __builtin_amdgcn_mfma_f32_16x16x32_bf16(a[mf], bcg, ca[mf][1], 0, 0, 0);
      }
      bca = bna;
      bcg = bng;
    }
    // GLU -> r4-packed u: lane's 4 rows = one uint2 (coalesced 128B per lhi-group)
    int ucol = pb * 16 + llo;
    float ba = ff1b[ucol], bg = ff1b[512 + ucol];
    int rb0 = (pix0 >> 2) + lhi;
#pragma unroll
    for (int mf = 0; mf < 6; ++mf) {
      ushort_t b0 = f2bf((ca[mf][0][0] + ba) * sigf(ca[mf][1][0] + bg));
      ushort_t b1 = f2bf((ca[mf][0][1] + ba) * sigf(ca[mf][1][1] + bg));
      ushort_t b2 = f2bf((ca[mf][0][2] + ba) * sigf(ca[mf][1][2] + bg));
      ushort_t b3 = f2bf((ca[mf][0][3] + ba) * sigf(ca[mf][1][3] + bg));
      uint2 pk;
      pk.x = (uint_t)b0 | ((uint_t)b1 << 16);
      pk.y = (uint_t)b2 | ((uint_t)b3 << 16);
      *(uint2*)(u + ((long)(rb0 + mf * 4) * 512 + ucol) * 4) = pk;
    }
  }
}

// ---------------- k_ff2: GEMM2 (u @ W2) + bias + residual (out +=), M=96 ----
// u is r4-packed. Reg-staged chunk double-buffer + direct float4 RMW epilogue.
__global__ __launch_bounds__(512, 4) void k_ff2(
    const ushort_t* __restrict__ u, const ushort_t* __restrict__ W2p,
    const float* __restrict__ ff2b, float* __restrict__ out) {
  __shared__ __align__(16) char pool[24576];  // uA 96x256B chunk

  int tid = threadIdx.x;
  int pix0 = blockIdx.x * 96;
  int n = pix0 / HWSZ, hw0 = pix0 % HWSZ;
  int rb0 = pix0 >> 2;

  int l = tid & 63, w = tid >> 6;
  int llo = l & 15, lhi = l >> 4;

  const uint4* W2p4 = (const uint4*)W2p;   // [kt16][nt16][64] uint4

  // preload chunk 0 into registers
  uint2 st[6];
#pragma unroll
  for (int t = 0; t < 6; ++t) {
    int i = t * 512 + tid;
    int col = i & 127, rbl = i >> 7;
    st[t] = *(const uint2*)(u + ((long)(rb0 + rbl) * 512 + col) * 4);
  }

  f32x4 zacc[6][2];
#pragma unroll
  for (int mf = 0; mf < 6; ++mf) {
    zacc[mf][0] = (f32x4){0.f, 0.f, 0.f, 0.f};
    zacc[mf][1] = (f32x4){0.f, 0.f, 0.f, 0.f};
  }

#pragma unroll
  for (int kc = 0; kc < 4; ++kc) {
    if (kc) __syncthreads();   // WAR: previous chunk reads done
    // scatter current chunk from regs into swizzled LDS
#pragma unroll
    for (int t = 0; t < 6; ++t) {
      int i = t * 512 + tid;
      int col = i & 127, rbl = i >> 7;
      int p = rbl * 4;
      ushort_t* b = (ushort_t*)&st[t];
#pragma unroll
      for (int k = 0; k < 4; ++k)
        *(ushort_t*)(pool + (p + k) * 256 + ((col * 2) ^ (((p + k) & 7) << 4))) = b[k];
    }
    __syncthreads();
    // issue next chunk loads (fly under MFMA)
    if (kc < 3) {
#pragma unroll
      for (int t = 0; t < 6; ++t) {
        int i = t * 512 + tid;
        int col = i & 127, rbl = i >> 7;
        st[t] = *(const uint2*)(u + ((long)(rb0 + rbl) * 512 + (kc + 1) * 128 + col) * 4);
      }
    }
#pragma unroll
    for (int ks = 0; ks < 4; ++ks) {
      int kt = kc * 4 + ks;
      short8x a[6];
#pragma unroll
      for (int mf = 0; mf < 6; ++mf) {
        int arow = mf * 16 + llo;
        a[mf] = *(const short8x*)(pool + arow * 256 +
                                  ((ks * 64 + lhi * 16) ^ ((arow & 7) << 4)));
      }
      short8x b0 = *(const short8x*)(W2p4 + (long)(kt * 16 + w * 2) * 64 + l);
      short8x b1 = *(const short8x*)(W2p4 + (long)(kt * 16 + w * 2 + 1) * 64 + l);
#pragma unroll
      for (int mf = 0; mf < 6; ++mf) {
        zacc[mf][0] = __builtin_amdgcn_mfma_f32_16x16x32_bf16(a[mf], b0, zacc[mf][0], 0, 0, 0);
        zacc[mf][1] = __builtin_amdgcn_mfma_f32_16x16x32_bf16(a[mf], b1, zacc[mf][1], 0, 0, 0);
      }
    }
  }

  // direct RMW epilogue: lane (mf,ntl) owns pixels hw0+mf*16+lhi*4..+3 at channel c
#pragma unroll
  for (int mf = 0; mf < 6; ++mf)
#pragma unroll
    for (int ntl = 0; ntl < 2; ++ntl) {
      int c = (w * 2 + ntl) * 16 + llo;
      float fb = ff2b[c];
      long addr = (long)(n * 256 + c) * HWSZ + hw0 + mf * 16 + lhi * 4;
      float4 ov = *(const float4*)(out + addr);
      ov.x += zacc[mf][ntl][0] + fb;
      ov.y += zacc[mf][ntl][1] + fb;
      ov.z += zacc[mf][ntl][2] + fb;
      ov.w += zacc[mf][ntl][3] + fb;
      *(float4*)(out + addr) = ov;
    }
}

extern "C" void kernel_launch(void* const* d_in, const int* in_sizes, int n_in,
                              void* d_out, int out_size, void* d_ws, size_t ws_size,
                              hipStream_t stream) {
  (void)in_sizes; (void)n_in; (void)out_size; (void)ws_size;
  const float* x     = (const float*)d_in[0];
  const float* ln1w  = (const float*)d_in[1];
  const float* ln1b  = (const float*)d_in[2];
  const float* dww   = (const float*)d_in[3];
  const float* dwb   = (const float*)d_in[4];
  const float* lr_w  = (const float*)d_in[5];
  const float* lr_b  = (const float*)d_in[6];
  const float* lr_gw = (const float*)d_in[7];
  const float* lr_gb = (const float*)d_in[8];
  const float* rl_w  = (const float*)d_in[9];
  const float* rl_b  = (const float*)d_in[10];
  const float* rl_gw = (const float*)d_in[11];
  const float* rl_gb = (const float*)d_in[12];
  const float* tb_w  = (const float*)d_in[13];
  const float* tb_b  = (const float*)d_in[14];
  const float* tb_gw = (const float*)d_in[15];
  const float* tb_gb = (const float*)d_in[16];
  const float* bt_w  = (const float*)d_in[17];
  const float* bt_b  = (const float*)d_in[18];
  const float* bt_gw = (const float*)d_in[19];
  const float* bt_gb = (const float*)d_in[20];
  const float* fusew = (const float*)d_in[21];
  const float* fuseb = (const float*)d_in[22];
  const float* ln2w  = (const float*)d_in[23];
  const float* ln2b  = (const float*)d_in[24];
  const float* ff1w  = (const float*)d_in[25];
  const float* ff1b  = (const float*)d_in[26];
  const float* ff2w  = (const float*)d_in[27];
  const float* ff2b  = (const float*)d_in[28];

  float* out = (float*)d_out;
  ushort_t* y  = (ushort_t*)d_ws;                 // 18874368 bf16
  ushort_t* yT = y + 18874368;                    // 18874368 bf16
  ushort_t* o  = yT + 18874368;                   // 18874368 bf16
  ushort_t* oT = o + 18874368;                    // 18874368 bf16
  ushort_t* uu = y;                               // aliases y+yT (dead by k_ff1)
  float* mean1 = (float*)(oT + 18874368);
  float* rstd1 = mean1 + 2048;
  float* mean2 = rstd1 + 2048;
  float* rstd2 = mean2 + 2048;
  ushort_t* Gp  = (ushort_t*)(rstd2 + 2048);      // 262144
  ushort_t* Ftp = Gp + 262144;                    // 65536
  ushort_t* W1p = Ftp + 65536;                    // 262144
  ushort_t* W2p = W1p + 262144;                   // 131072

  k_pack<<<2816, TPB, 0, stream>>>(lr_gw, rl_gw, tb_gw, bt_gw, fusew, ff1w, ff2w,
                                   Gp, Ftp, W1p, W2p);
  k_stats<<<2048, TPB, 0, stream>>>(x, mean1, rstd1);
  k_lndw<<<1536, TPB, 0, stream>>>(x, mean1, rstd1, ln1w, ln1b, dww, dwb, y, yT);
  k_scan<<<1536, 512, 0, stream>>>(y, (const uint4*)Gp,
                                   lr_w, lr_b, lr_gb, rl_w, rl_b, rl_gb, o);
  k_scan<<<1536, 512, 0, stream>>>(yT, (const uint4*)(Gp + 131072),
                                   tb_w, tb_b, tb_gb, bt_w, bt_b, bt_gb, oT);
  k_fuse<<<1536, 512, 0, stream>>>(o, oT, Ftp, fuseb, x, out);
  k_stats<<<2048, TPB, 0, stream>>>(out, mean2, rstd2);
  k_ff1<<<768, 512, 0, stream>>>(out, mean2, rstd2, ln2w, ln2b, W1p, ff1b, uu);
  k_ff2<<<768, 512, 0, stream>>>(uu, W2p, ff2b, out);
}

// Round 14
// 313.917 us; speedup vs baseline: 1.1053x; 1.0148x over previous
//
#include <hip/hip_runtime.h>

#define TPB 256
#define HWSZ 9216      // 96*96

typedef __attribute__((ext_vector_type(8))) short short8x;
typedef __attribute__((ext_vector_type(4))) float f32x4;
typedef unsigned short ushort_t;
typedef unsigned int uint_t;

__device__ __forceinline__ float sigf(float v) { return 1.0f / (1.0f + __expf(-v)); }

// HW bf16 conversion (RNE): fptrunc -> v_cvt_pk_bf16_f32 on gfx950.
__device__ __forceinline__ ushort_t f2bf(float f) {
  __bf16 h = (__bf16)f;
  return __builtin_bit_cast(ushort_t, h);
}
__device__ __forceinline__ float bf2f(ushort_t h) {
  return __uint_as_float(((uint_t)h) << 16);
}

// ---------------- pack weights to fragment-major bf16 ----------------
// 16x16x32 B-frag tile(kt,nt): elem(l,j) = B[kt*32+(l>>4)*8+j][nt*16+(l&15)]
// Gp:  [dir4][kt8][nt16][64][8]
// Ftp: [kt8][nt16][64][8]
// W1p: [kt8][pb32][ag2][64][8]  (pair-block pb = u-cols pb*16..+15; ag=0 a, 1 g)
// W2p: [kt16][nt16][64][8]
__global__ __launch_bounds__(TPB) void k_pack(
    const float* __restrict__ lrg, const float* __restrict__ rlg,
    const float* __restrict__ tbg, const float* __restrict__ btg,
    const float* __restrict__ fusew, const float* __restrict__ ff1w,
    const float* __restrict__ ff2w,
    ushort_t* __restrict__ Gp, ushort_t* __restrict__ Ftp,
    ushort_t* __restrict__ W1p, ushort_t* __restrict__ W2p) {
  int i = blockIdx.x * TPB + threadIdx.x;
  if (i < 262144) {
    int d = i >> 16, r = i & 65535;
    int kt = r >> 13, nt = (r >> 9) & 15, l = (r >> 3) & 63, j = r & 7;
    int k = kt * 32 + (l >> 4) * 8 + j;
    int n_ = nt * 16 + (l & 15);
    const float* g = (d == 0) ? lrg : (d == 1) ? rlg : (d == 2) ? tbg : btg;
    Gp[i] = f2bf(g[n_ * 256 + k]);
  } else if (i < 327680) {
    int r = i - 262144;
    int kt = r >> 13, nt = (r >> 9) & 15, l = (r >> 3) & 63, j = r & 7;
    int k = kt * 32 + (l >> 4) * 8 + j;
    int n_ = nt * 16 + (l & 15);
    Ftp[r] = f2bf(fusew[n_ * 256 + k]);
  } else if (i < 589824) {
    int r = i - 327680;
    int kt = r >> 15, pb = (r >> 10) & 31, ag = (r >> 9) & 1;
    int l = (r >> 3) & 63, j = r & 7;
    int k = kt * 32 + (l >> 4) * 8 + j;
    int colb = pb * 16 + (l & 15);
    int col = ag ? (512 + colb) : colb;
    W1p[r] = f2bf(ff1w[col * 256 + k]);
  } else if (i < 720896) {
    int r = i - 589824;
    int kt = r >> 13, nt = (r >> 9) & 15, l = (r >> 3) & 63, j = r & 7;
    int k = kt * 32 + (l >> 4) * 8 + j;
    int n_ = nt * 16 + (l & 15);
    W2p[r] = f2bf(ff2w[n_ * 512 + k]);
  }
}

// ---------------- per-(n,c) LayerNorm2d stats (float4) ----------------
__global__ __launch_bounds__(TPB) void k_stats(const float* __restrict__ src,
                                               float* __restrict__ mean,
                                               float* __restrict__ rstd) {
  int nc = blockIdx.x;
  const float4* p = (const float4*)(src + (long)nc * HWSZ);
  float s = 0.f, s2 = 0.f;
  for (int i = threadIdx.x; i < 2304; i += TPB) {
    float4 v = p[i];
    s += (v.x + v.y) + (v.z + v.w);
    s2 = fmaf(v.x, v.x, fmaf(v.y, v.y, fmaf(v.z, v.z, fmaf(v.w, v.w, s2))));
  }
#pragma unroll
  for (int off = 32; off > 0; off >>= 1) {
    s += __shfl_down(s, off);
    s2 += __shfl_down(s2, off);
  }
  __shared__ float ls[4], ls2[4];
  int lane = threadIdx.x & 63, wv = threadIdx.x >> 6;
  if (lane == 0) { ls[wv] = s; ls2[wv] = s2; }
  __syncthreads();
  if (threadIdx.x == 0) {
    float S = ls[0] + ls[1] + ls[2] + ls[3];
    float S2 = ls2[0] + ls2[1] + ls2[2] + ls2[3];
    float m = S * (1.0f / HWSZ);
    float var = S2 * (1.0f / HWSZ) - m * m;
    mean[nc] = m;
    rstd[nc] = rsqrtf(fmaxf(var, 0.f) + 1e-6f);
  }
}

// ---------------- ln1 + depthwise 3x3 -> y (NHWC) and yT (transposed) -------
// Block = (n, 4-row band, 32-ch group). Grid 8*24*8 = 1536.
__global__ __launch_bounds__(TPB) void k_lndw(
    const float* __restrict__ x, const float* __restrict__ mean1,
    const float* __restrict__ rstd1, const float* __restrict__ ln1w,
    const float* __restrict__ ln1b, const float* __restrict__ dww,
    const float* __restrict__ dwb, ushort_t* __restrict__ y,
    ushort_t* __restrict__ yT) {
  __shared__ __align__(16) ushort_t xs[6 * 32 * 104];   // 39936 B
  __shared__ __align__(16) ushort_t ot[2 * 96 * 32];    // 12288 B
  __shared__ float sc[32], sh[32];

  int tid = threadIdx.x;
  int bid = blockIdx.x;
  int cb = (bid & 7) * 32;
  int hb = (bid >> 3) % 24;
  int n  = bid / 192;
  int h0 = hb * 4;

  if (tid < 32) {
    int c = cb + tid;
    int nc = n * 256 + c;
    float scale = rstd1[nc] * ln1w[c];
    sc[tid] = scale;
    sh[tid] = ln1b[c] - mean1[nc] * scale;
  }
  if (tid < 192) {   // w halos
    xs[tid * 104 + 3] = 0;
    xs[tid * 104 + 100] = 0;
  }
  __syncthreads();

  // stage 6 LN'd rows (h0-1 .. h0+4), float4 loads -> bf16x4 stores
  for (int i = tid; i < 4608; i += TPB) {
    int rc = i / 24;            // 0..191  (row*32 + c)
    int f4 = i - rc * 24;       // 0..23
    int row = rc >> 5, c = rc & 31;
    int hh = h0 - 1 + row;
    uint2 pk = make_uint2(0, 0);
    if (hh >= 0 && hh < 96) {
      float4 v = *(const float4*)(x + (long)(n * 256 + cb + c) * HWSZ +
                                  hh * 96 + f4 * 4);
      float scale = sc[c], shift = sh[c];
      ushort_t p0 = f2bf(fmaf(v.x, scale, shift));
      ushort_t p1 = f2bf(fmaf(v.y, scale, shift));
      ushort_t p2 = f2bf(fmaf(v.z, scale, shift));
      ushort_t p3 = f2bf(fmaf(v.w, scale, shift));
      pk.x = (uint_t)p0 | ((uint_t)p1 << 16);
      pk.y = (uint_t)p2 | ((uint_t)p3 << 16);
    }
    *(uint2*)(xs + rc * 104 + 4 + f4 * 4) = pk;
  }
  __syncthreads();

  // conv: thread = (c = tid&31, 12-w group grp = tid>>5)
  int c = tid & 31, grp = tid >> 5;
  int w0 = grp * 12;
  float wgt[9];
#pragma unroll
  for (int t = 0; t < 9; ++t) wgt[t] = dww[t * 256 + cb + c];
  float bias = dwb[cb + c];

#pragma unroll
  for (int half = 0; half < 2; ++half) {
    float vals[2][12];
#pragma unroll
    for (int sub = 0; sub < 2; ++sub) {
      int orow = half * 2 + sub;
      float R[3][14];
#pragma unroll
      for (int rr = 0; rr < 3; ++rr) {
        const ushort_t* p = xs + ((orow + rr) * 32 + c) * 104;
        R[rr][0] = bf2f(p[3 + w0]);
        ushort4 q0 = *(const ushort4*)(p + 4 + w0);
        ushort4 q1 = *(const ushort4*)(p + 8 + w0);
        ushort4 q2 = *(const ushort4*)(p + 12 + w0);
        R[rr][1] = bf2f(q0.x);  R[rr][2] = bf2f(q0.y);
        R[rr][3] = bf2f(q0.z);  R[rr][4] = bf2f(q0.w);
        R[rr][5] = bf2f(q1.x);  R[rr][6] = bf2f(q1.y);
        R[rr][7] = bf2f(q1.z);  R[rr][8] = bf2f(q1.w);
        R[rr][9] = bf2f(q2.x);  R[rr][10] = bf2f(q2.y);
        R[rr][11] = bf2f(q2.z); R[rr][12] = bf2f(q2.w);
        R[rr][13] = bf2f(p[16 + w0]);
      }
#pragma unroll
      for (int k = 0; k < 12; ++k) {
        float acc = bias;
#pragma unroll
        for (int rr = 0; rr < 3; ++rr) {
          acc = fmaf(R[rr][k], wgt[rr * 3 + 0], acc);
          acc = fmaf(R[rr][k + 1], wgt[rr * 3 + 1], acc);
          acc = fmaf(R[rr][k + 2], wgt[rr * 3 + 2], acc);
        }
        vals[sub][k] = acc;
      }
    }
    if (half == 1) __syncthreads();  // protect ot from half-0 readers
#pragma unroll
    for (int sub = 0; sub < 2; ++sub)
#pragma unroll
      for (int k = 0; k < 12; ++k)
        ot[(sub * 96 + w0 + k) * 32 + c] = f2bf(vals[sub][k]);
    __syncthreads();
#pragma unroll
    for (int it = 0; it < 3; ++it) {
      int u = it * 256 + tid;
      int r2 = (u >= 384) ? 1 : 0;
      int rem = u - r2 * 384;
      int w = rem >> 2, cq = rem & 3;
      uint4 v = *(const uint4*)(ot + (r2 * 96 + w) * 32 + cq * 8);
      int h = h0 + half * 2 + r2;
      *(uint4*)(y + ((long)(n * 96 + h) * 96 + w) * 256 + cb + cq * 8) = v;
      *(uint4*)(yT + ((long)(n * 96 + w) * 96 + h) * 256 + cb + cq * 8) = v;
    }
  }
}

// ---------------- unified scan: gate GEMM + dwconv1d*sigmoid (streaming) ----
__global__ __launch_bounds__(512, 4) void k_scan(
    const ushort_t* __restrict__ src, const uint4* __restrict__ gp4,
    const float* __restrict__ dwaw, const float* __restrict__ dwab,
    const float* __restrict__ gab, const float* __restrict__ dwbw,
    const float* __restrict__ dwbb, const float* __restrict__ gbb,
    ushort_t* __restrict__ dst) {
  __shared__ __align__(16) char pool[34816];
  char* ylds = pool;            // 52 rows x 512B, swizzled (pixel q at row q-p0+2)
  char* olds = pool + 26624;    // 16 rows x 512B chunk, swizzled

  int tid = threadIdx.x;
  int bid = blockIdx.x;
  int seg = bid & 1, line = (bid >> 1) % 96, n = bid / 192;
  int p0 = seg * 48;
  long lbase = (long)(n * 96 + line) * 96;

  for (int u = tid; u < 52 * 32; u += 512) {
    int r = u >> 5, ks = u & 31;
    int q = p0 - 2 + r;
    uint4 v = make_uint4(0, 0, 0, 0);
    if (q >= 0 && q < 96)
      v = *(const uint4*)(src + (lbase + q) * 256 + ks * 8);
    *(uint4*)(ylds + r * 512 + ((ks * 16) ^ ((r & 7) << 4))) = v;
  }
  __syncthreads();

  int l = tid & 63, w = tid >> 6;
  int llo = l & 15, lhi = l >> 4;

  float part[3][2][4];

#pragma unroll
  for (int diri = 0; diri < 2; ++diri) {
    f32x4 acc[3][2];
#pragma unroll
    for (int mf = 0; mf < 3; ++mf)
#pragma unroll
      for (int ntl = 0; ntl < 2; ++ntl) acc[mf][ntl] = (f32x4){0.f, 0.f, 0.f, 0.f};

    const uint4* gbase = gp4 + ((long)(diri * 8) * 16 + w * 2) * 64 + l;
    short8x bc0 = *(const short8x*)(gbase);
    short8x bc1 = *(const short8x*)(gbase + 64);
#pragma unroll
    for (int kt = 0; kt < 8; ++kt) {
      short8x bn0, bn1;
      if (kt < 7) {
        bn0 = *(const short8x*)(gbase + (kt + 1) * 1024);
        bn1 = *(const short8x*)(gbase + (kt + 1) * 1024 + 64);
      }
      short8x a[3];
#pragma unroll
      for (int mf = 0; mf < 3; ++mf) {
        int arow = 2 + mf * 16 + llo;
        a[mf] = *(const short8x*)(ylds + arow * 512 +
                                  ((kt * 64 + lhi * 16) ^ ((arow & 7) << 4)));
      }
#pragma unroll
      for (int mf = 0; mf < 3; ++mf) {
        acc[mf][0] = __builtin_amdgcn_mfma_f32_16x16x32_bf16(a[mf], bc0, acc[mf][0], 0, 0, 0);
        acc[mf][1] = __builtin_amdgcn_mfma_f32_16x16x32_bf16(a[mf], bc1, acc[mf][1], 0, 0, 0);
      }
      bc0 = bn0;
      bc1 = bn1;
    }

    const float* dwv = diri ? dwbw : dwaw;
    const float* dbv = diri ? dwbb : dwab;
    const float* gbv = diri ? gbb : gab;
#pragma unroll
    for (int ntl = 0; ntl < 2; ++ntl) {
      int c = (w * 2 + ntl) * 16 + llo;
      float wt[5];
#pragma unroll
      for (int t = 0; t < 5; ++t)
        wt[t] = diri ? dwv[(4 - t) * 256 + c] : dwv[t * 256 + c];
      float cb = dbv[c], gb = gbv[c];
#pragma unroll
      for (int mf = 0; mf < 3; ++mf) {
        int pbase = mf * 16 + lhi * 4;
        float yv[8];
#pragma unroll
        for (int t = 0; t < 8; ++t) {
          int ry = pbase + t;
          yv[t] = bf2f(*(const ushort_t*)(ylds + ry * 512 +
                                          ((c * 2) ^ ((ry & 7) << 4))));
        }
#pragma unroll
        for (int r = 0; r < 4; ++r) {
          float conv = cb;
#pragma unroll
          for (int t = 0; t < 5; ++t) conv = fmaf(yv[r + t], wt[t], conv);
          float val = conv * sigf(acc[mf][ntl][r] + gb);
          if (diri == 0) part[mf][ntl][r] = val;
          else           part[mf][ntl][r] += val;
        }
      }
    }
  }

  // 3-pass chunked streaming output (16 rows each), no RMW
#pragma unroll
  for (int mf = 0; mf < 3; ++mf) {
    __syncthreads();
#pragma unroll
    for (int ntl = 0; ntl < 2; ++ntl) {
      int c = (w * 2 + ntl) * 16 + llo;
#pragma unroll
      for (int r = 0; r < 4; ++r) {
        int p = lhi * 4 + r;
        *(ushort_t*)(olds + p * 512 + ((c * 2) ^ ((p & 7) << 4))) =
            f2bf(part[mf][ntl][r]);
      }
    }
    __syncthreads();
    {
      int p = tid >> 5, ks = tid & 31;
      uint4 v = *(const uint4*)(olds + p * 512 + ((ks * 16) ^ ((p & 7) << 4)));
      *(uint4*)(dst + (lbase + p0 + mf * 16 + p) * 256 + ks * 8) = v;
    }
  }
}

// ---------------- fuse GEMM + residual: out(NCHW) = x + (o+oT')@Ft + b -------
// M=48/block, 8 waves, wave w owns nt {w*2, w*2+1}; mf=3.
// Direct float4 epilogue (lane's 4 MFMA rows = 4 consecutive pixels).
__global__ __launch_bounds__(512, 4) void k_fuse(
    const ushort_t* __restrict__ o, const ushort_t* __restrict__ oT,
    const ushort_t* __restrict__ Ftp, const float* __restrict__ fuseb,
    const float* __restrict__ x, float* __restrict__ out) {
  __shared__ __align__(16) char pool[24576];  // alds 48x512B

  int tid = threadIdx.x;
  int pix0 = blockIdx.x * 48;
  int n = pix0 / HWSZ, hw0 = pix0 % HWSZ;
  int h = hw0 / 96, w0 = hw0 % 96;

  for (int u = tid; u < 48 * 32; u += 512) {
    int r = u >> 5, ks = u & 31;
    uint4 va = *(const uint4*)(o + (long)(pix0 + r) * 256 + ks * 8);
    uint4 vb = *(const uint4*)(oT + ((long)(n * 96 + w0 + r) * 96 + h) * 256 + ks * 8);
    ushort_t* a8 = (ushort_t*)&va;
    ushort_t* b8 = (ushort_t*)&vb;
#pragma unroll
    for (int j = 0; j < 8; ++j) a8[j] = f2bf(bf2f(a8[j]) + bf2f(b8[j]));
    *(uint4*)(pool + r * 512 + ((ks * 16) ^ ((r & 7) << 4))) = va;
  }
  __syncthreads();

  int l = tid & 63, w = tid >> 6;
  int llo = l & 15, lhi = l >> 4;

  const uint4* fp4 = (const uint4*)Ftp;
  f32x4 acc[3][2];
#pragma unroll
  for (int mf = 0; mf < 3; ++mf)
#pragma unroll
    for (int ntl = 0; ntl < 2; ++ntl) acc[mf][ntl] = (f32x4){0.f, 0.f, 0.f, 0.f};

  const uint4* fbase = fp4 + (long)(w * 2) * 64 + l;
  short8x bc0 = *(const short8x*)(fbase);
  short8x bc1 = *(const short8x*)(fbase + 64);
#pragma unroll
  for (int kt = 0; kt < 8; ++kt) {
    short8x bn0, bn1;
    if (kt < 7) {
      bn0 = *(const short8x*)(fbase + (kt + 1) * 1024);
      bn1 = *(const short8x*)(fbase + (kt + 1) * 1024 + 64);
    }
    short8x a[3];
#pragma unroll
    for (int mf = 0; mf < 3; ++mf) {
      int arow = mf * 16 + llo;
      a[mf] = *(const short8x*)(pool + arow * 512 +
                                ((kt * 64 + lhi * 16) ^ ((arow & 7) << 4)));
    }
#pragma unroll
    for (int mf = 0; mf < 3; ++mf) {
      acc[mf][0] = __builtin_amdgcn_mfma_f32_16x16x32_bf16(a[mf], bc0, acc[mf][0], 0, 0, 0);
      acc[mf][1] = __builtin_amdgcn_mfma_f32_16x16x32_bf16(a[mf], bc1, acc[mf][1], 0, 0, 0);
    }
    bc0 = bn0;
    bc1 = bn1;
  }

  // direct epilogue: lane (mf,ntl) owns pixels hw0+mf*16+lhi*4..+3 at channel c
#pragma unroll
  for (int mf = 0; mf < 3; ++mf)
#pragma unroll
    for (int ntl = 0; ntl < 2; ++ntl) {
      int c = (w * 2 + ntl) * 16 + llo;
      float fb = fuseb[c];
      long addr = (long)(n * 256 + c) * HWSZ + hw0 + mf * 16 + lhi * 4;
      float4 xv = *(const float4*)(x + addr);
      float4 ov;
      ov.x = xv.x + acc[mf][ntl][0] + fb;
      ov.y = xv.y + acc[mf][ntl][1] + fb;
      ov.z = xv.z + acc[mf][ntl][2] + fb;
      ov.w = xv.w + acc[mf][ntl][3] + fb;
      *(float4*)(out + addr) = ov;
    }
}

// ---------------- k_ff1: ln2 + GEMM1 + GLU -> u (r4-packed bf16), M=96 -------
// u layout: u[(row>>2)][col512][row&3] bf16 -> lane's 4 MFMA rows = one uint2.
__global__ __launch_bounds__(512, 4) void k_ff1(
    const float* __restrict__ xres, const float* __restrict__ mean2,
    const float* __restrict__ rstd2, const float* __restrict__ ln2w,
    const float* __restrict__ ln2b, const ushort_t* __restrict__ W1p,
    const float* __restrict__ ff1b, ushort_t* __restrict__ u) {
  __shared__ char hA[96 * 512];   // 48KB, XOR-swizzled
  __shared__ float sc[256], sh[256];

  int tid = threadIdx.x;
  int pix0 = blockIdx.x * 96;
  int n = pix0 / HWSZ, hw0 = pix0 % HWSZ;

  if (tid < 256) {
    int nc = n * 256 + tid;
    float scale = rstd2[nc] * ln2w[tid];
    sc[tid] = scale;
    sh[tid] = ln2b[tid] - mean2[nc] * scale;
  }
  __syncthreads();

  // staging: 2 channels x 2 pixels per iteration, packed uint LDS stores
  for (int i = tid; i < 6144; i += 512) {
    int cp = i / 48, pp = i % 48;
    int c0 = cp * 2;
    long base0 = (long)(n * 256 + c0) * HWSZ + hw0 + pp * 2;
    float2 v0 = *(const float2*)(xres + base0);
    float2 v1 = *(const float2*)(xres + base0 + HWSZ);
    float s0 = sc[c0], h0 = sh[c0];
    float s1 = sc[c0 + 1], h1 = sh[c0 + 1];
    int p0 = pp * 2;
    uint_t w0 = (uint_t)f2bf(fmaf(v0.x, s0, h0)) |
                ((uint_t)f2bf(fmaf(v1.x, s1, h1)) << 16);
    uint_t w1 = (uint_t)f2bf(fmaf(v0.y, s0, h0)) |
                ((uint_t)f2bf(fmaf(v1.y, s1, h1)) << 16);
    *(uint_t*)(hA + p0 * 512 + ((c0 * 2) ^ ((p0 & 7) << 4))) = w0;
    *(uint_t*)(hA + (p0 + 1) * 512 + ((c0 * 2) ^ (((p0 + 1) & 7) << 4))) = w1;
  }
  __syncthreads();

  int l = tid & 63, w = tid >> 6;
  int llo = l & 15, lhi = l >> 4;

  const uint4* W1p4 = (const uint4*)W1p;   // [kt8][pb32][ag2][64] uint4
#pragma unroll
  for (int q = 0; q < 4; ++q) {
    int pb = q * 8 + w;
    f32x4 ca[6][2];
#pragma unroll
    for (int mf = 0; mf < 6; ++mf) {
      ca[mf][0] = (f32x4){0.f, 0.f, 0.f, 0.f};
      ca[mf][1] = (f32x4){0.f, 0.f, 0.f, 0.f};
    }
    const uint4* wb = W1p4 + (long)(pb * 2) * 64 + l;   // kt stride = 4096 uint4
    short8x bca = *(const short8x*)(wb);
    short8x bcg = *(const short8x*)(wb + 64);
#pragma unroll
    for (int kt = 0; kt < 8; ++kt) {
      short8x bna, bng;
      if (kt < 7) {
        bna = *(const short8x*)(wb + (kt + 1) * 4096);
        bng = *(const short8x*)(wb + (kt + 1) * 4096 + 64);
      }
      short8x a[6];
#pragma unroll
      for (int mf = 0; mf < 6; ++mf) {
        int arow = mf * 16 + llo;
        a[mf] = *(const short8x*)(hA + arow * 512 +
                                  ((kt * 64 + lhi * 16) ^ ((arow & 7) << 4)));
      }
#pragma unroll
      for (int mf = 0; mf < 6; ++mf) {
        ca[mf][0] = __builtin_amdgcn_mfma_f32_16x16x32_bf16(a[mf], bca, ca[mf][0], 0, 0, 0);
        ca[mf][1] = __builtin_amdgcn_mfma_f32_16x16x32_bf16(a[mf], bcg, ca[mf][1], 0, 0, 0);
      }
      bca = bna;
      bcg = bng;
    }
    // GLU -> r4-packed u: lane's 4 rows = one uint2 (coalesced 128B per lhi-group)
    int ucol = pb * 16 + llo;
    float ba = ff1b[ucol], bg = ff1b[512 + ucol];
    int rb0 = (pix0 >> 2) + lhi;
#pragma unroll
    for (int mf = 0; mf < 6; ++mf) {
      ushort_t b0 = f2bf((ca[mf][0][0] + ba) * sigf(ca[mf][1][0] + bg));
      ushort_t b1 = f2bf((ca[mf][0][1] + ba) * sigf(ca[mf][1][1] + bg));
      ushort_t b2 = f2bf((ca[mf][0][2] + ba) * sigf(ca[mf][1][2] + bg));
      ushort_t b3 = f2bf((ca[mf][0][3] + ba) * sigf(ca[mf][1][3] + bg));
      uint2 pk;
      pk.x = (uint_t)b0 | ((uint_t)b1 << 16);
      pk.y = (uint_t)b2 | ((uint_t)b3 << 16);
      *(uint2*)(u + ((long)(rb0 + mf * 4) * 512 + ucol) * 4) = pk;
    }
  }
}

// ---------------- k_ff2: GEMM2 (u @ W2) + bias + residual (out +=), M=96 ----
// u is r4-packed. Reg-staged chunk double-buffer + direct float4 RMW epilogue.
__global__ __launch_bounds__(512, 4) void k_ff2(
    const ushort_t* __restrict__ u, const ushort_t* __restrict__ W2p,
    const float* __restrict__ ff2b, float* __restrict__ out) {
  __shared__ __align__(16) char pool[24576];  // uA 96x256B chunk

  int tid = threadIdx.x;
  int pix0 = blockIdx.x * 96;
  int n = pix0 / HWSZ, hw0 = pix0 % HWSZ;
  int rb0 = pix0 >> 2;

  int l = tid & 63, w = tid >> 6;
  int llo = l & 15, lhi = l >> 4;

  const uint4* W2p4 = (const uint4*)W2p;   // [kt16][nt16][64] uint4

  // preload chunk 0 into registers
  uint2 st[6];
#pragma unroll
  for (int t = 0; t < 6; ++t) {
    int i = t * 512 + tid;
    int col = i & 127, rbl = i >> 7;
    st[t] = *(const uint2*)(u + ((long)(rb0 + rbl) * 512 + col) * 4);
  }

  f32x4 zacc[6][2];
#pragma unroll
  for (int mf = 0; mf < 6; ++mf) {
    zacc[mf][0] = (f32x4){0.f, 0.f, 0.f, 0.f};
    zacc[mf][1] = (f32x4){0.f, 0.f, 0.f, 0.f};
  }

#pragma unroll
  for (int kc = 0; kc < 4; ++kc) {
    if (kc) __syncthreads();   // WAR: previous chunk reads done
    // scatter current chunk from regs into swizzled LDS
#pragma unroll
    for (int t = 0; t < 6; ++t) {
      int i = t * 512 + tid;
      int col = i & 127, rbl = i >> 7;
      int p = rbl * 4;
      ushort_t* b = (ushort_t*)&st[t];
#pragma unroll
      for (int k = 0; k < 4; ++k)
        *(ushort_t*)(pool + (p + k) * 256 + ((col * 2) ^ (((p + k) & 7) << 4))) = b[k];
    }
    __syncthreads();
    // issue next chunk loads (fly under MFMA)
    if (kc < 3) {
#pragma unroll
      for (int t = 0; t < 6; ++t) {
        int i = t * 512 + tid;
        int col = i & 127, rbl = i >> 7;
        st[t] = *(const uint2*)(u + ((long)(rb0 + rbl) * 512 + (kc + 1) * 128 + col) * 4);
      }
    }
#pragma unroll
    for (int ks = 0; ks < 4; ++ks) {
      int kt = kc * 4 + ks;
      short8x a[6];
#pragma unroll
      for (int mf = 0; mf < 6; ++mf) {
        int arow = mf * 16 + llo;
        a[mf] = *(const short8x*)(pool + arow * 256 +
                                  ((ks * 64 + lhi * 16) ^ ((arow & 7) << 4)));
      }
      short8x b0 = *(const short8x*)(W2p4 + (long)(kt * 16 + w * 2) * 64 + l);
      short8x b1 = *(const short8x*)(W2p4 + (long)(kt * 16 + w * 2 + 1) * 64 + l);
#pragma unroll
      for (int mf = 0; mf < 6; ++mf) {
        zacc[mf][0] = __builtin_amdgcn_mfma_f32_16x16x32_bf16(a[mf], b0, zacc[mf][0], 0, 0, 0);
        zacc[mf][1] = __builtin_amdgcn_mfma_f32_16x16x32_bf16(a[mf], b1, zacc[mf][1], 0, 0, 0);
      }
    }
  }

  // direct RMW epilogue: lane (mf,ntl) owns pixels hw0+mf*16+lhi*4..+3 at channel c
#pragma unroll
  for (int mf = 0; mf < 6; ++mf)
#pragma unroll
    for (int ntl = 0; ntl < 2; ++ntl) {
      int c = (w * 2 + ntl) * 16 + llo;
      float fb = ff2b[c];
      long addr = (long)(n * 256 + c) * HWSZ + hw0 + mf * 16 + lhi * 4;
      float4 ov = *(const float4*)(out + addr);
      ov.x += zacc[mf][ntl][0] + fb;
      ov.y += zacc[mf][ntl][1] + fb;
      ov.z += zacc[mf][ntl][2] + fb;
      ov.w += zacc[mf][ntl][3] + fb;
      *(float4*)(out + addr) = ov;
    }
}

extern "C" void kernel_launch(void* const* d_in, const int* in_sizes, int n_in,
                              void* d_out, int out_size, void* d_ws, size_t ws_size,
                              hipStream_t stream) {
  (void)in_sizes; (void)n_in; (void)out_size; (void)ws_size;
  const float* x     = (const float*)d_in[0];
  const float* ln1w  = (const float*)d_in[1];
  const float* ln1b  = (const float*)d_in[2];
  const float* dww   = (const float*)d_in[3];
  const float* dwb   = (const float*)d_in[4];
  const float* lr_w  = (const float*)d_in[5];
  const float* lr_b  = (const float*)d_in[6];
  const float* lr_gw = (const float*)d_in[7];
  const float* lr_gb = (const float*)d_in[8];
  const float* rl_w  = (const float*)d_in[9];
  const float* rl_b  = (const float*)d_in[10];
  const float* rl_gw = (const float*)d_in[11];
  const float* rl_gb = (const float*)d_in[12];
  const float* tb_w  = (const float*)d_in[13];
  const float* tb_b  = (const float*)d_in[14];
  const float* tb_gw = (const float*)d_in[15];
  const float* tb_gb = (const float*)d_in[16];
  const float* bt_w  = (const float*)d_in[17];
  const float* bt_b  = (const float*)d_in[18];
  const float* bt_gw = (const float*)d_in[19];
  const float* bt_gb = (const float*)d_in[20];
  const float* fusew = (const float*)d_in[21];
  const float* fuseb = (const float*)d_in[22];
  const float* ln2w  = (const float*)d_in[23];
  const float* ln2b  = (const float*)d_in[24];
  const float* ff1w  = (const float*)d_in[25];
  const float* ff1b  = (const float*)d_in[26];
  const float* ff2w  = (const float*)d_in[27];
  const float* ff2b  = (const float*)d_in[28];

  float* out = (float*)d_out;
  ushort_t* y  = (ushort_t*)d_ws;                 // 18874368 bf16
  ushort_t* yT = y + 18874368;                    // 18874368 bf16
  ushort_t* o  = yT + 18874368;                   // 18874368 bf16
  ushort_t* oT = o + 18874368;                    // 18874368 bf16
  ushort_t* uu = y;                               // aliases y+yT (dead by k_ff1)
  float* mean1 = (float*)(oT + 18874368);
  float* rstd1 = mean1 + 2048;
  float* mean2 = rstd1 + 2048;
  float* rstd2 = mean2 + 2048;
  ushort_t* Gp  = (ushort_t*)(rstd2 + 2048);      // 262144
  ushort_t* Ftp = Gp + 262144;                    // 65536
  ushort_t* W1p = Ftp + 65536;                    // 262144
  ushort_t* W2p = W1p + 262144;                   // 131072

  k_pack<<<2816, TPB, 0, stream>>>(lr_gw, rl_gw, tb_gw, bt_gw, fusew, ff1w, ff2w,
                                   Gp, Ftp, W1p, W2p);
  k_stats<<<2048, TPB, 0, stream>>>(x, mean1, rstd1);
  k_lndw<<<1536, TPB, 0, stream>>>(x, mean1, rstd1, ln1w, ln1b, dww, dwb, y, yT);
  k_scan<<<1536, 512, 0, stream>>>(y, (const uint4*)Gp,
                                   lr_w, lr_b, lr_gb, rl_w, rl_b, rl_gb, o);
  k_scan<<<1536, 512, 0, stream>>>(yT, (const uint4*)(Gp + 131072),
                                   tb_w, tb_b, tb_gb, bt_w, bt_b, bt_gb, oT);
  k_fuse<<<1536, 512, 0, stream>>>(o, oT, Ftp, fuseb, x, out);
  k_stats<<<2048, TPB, 0, stream>>>(out, mean2, rstd2);
  k_ff1<<<768, 512, 0, stream>>>(out, mean2, rstd2, ln2w, ln2b, W1p, ff1b, uu);
  k_ff2<<<768, 512, 0, stream>>>(uu, W2p, ff2b, out);
}